// Round 12
// baseline (271.191 us; speedup 1.0000x reference)
//
#include <hip/hip_runtime.h>
#include <math.h>

#define B 8
#define S 4096
#define H 2048
#define LSYM 8
#define EMB 64
#define SPLIT 64
#define CHUNK (S / SPLIT)   // 64 rows per slab

typedef float f32x4 __attribute__((ext_vector_type(4)));

// ---------------- Kernel 1: partial pooling + last-block-per-b final reduce ----------------
// Main phase identical to R11 pool_partial (plain loads -> hid allocates in L3).
// Tail: per-b counter; the 64th block for batch b reduces part[:,b,:] -> pooled[b].
// Counters are monotone (never reset): each launch adds exactly 64 per b, so
// exactly one block sees (old & 63) == 63 regardless of the counter's start value.
__global__ __launch_bounds__(256) void pool_partial_fused(const float* __restrict__ hid,
                                                          float* __restrict__ part,
                                                          float* __restrict__ pooled,
                                                          unsigned int* __restrict__ cnt) {
    const int sp = blockIdx.x;          // 0..SPLIT-1
    const int b  = blockIdx.y;
    const int t  = threadIdx.x;
    const float* slab = hid + (size_t)b * S * H + (size_t)sp * CHUNK * H;
    const int iters = CHUNK * (H / 1024);   // 128
    f32x4 a[8];
#pragma unroll
    for (int k = 0; k < 8; ++k) a[k] = (f32x4)(0.f);
    for (int i = 0; i < iters; i += 8) {
#pragma unroll
        for (int k = 0; k < 8; ++k) {
            const f32x4 v = *reinterpret_cast<const f32x4*>(slab + (size_t)(i + k) * 1024 + t * 4);
            a[k] += v;
        }
    }
    const f32x4 e = a[0] + a[2] + a[4] + a[6];
    const f32x4 o = a[1] + a[3] + a[5] + a[7];
    float* dst = part + ((size_t)sp * B + b) * H;
    *reinterpret_cast<f32x4*>(dst + t * 4)        = e;
    *reinterpret_cast<f32x4*>(dst + 1024 + t * 4) = o;

    // ---- tail: last block for this b reduces all partials
    __syncthreads();
    __threadfence();                     // release our part writes device-wide
    __shared__ int is_last;
    if (t == 0) {
        const unsigned int old = __hip_atomic_fetch_add(&cnt[b * 32], 1u,
                                   __ATOMIC_ACQ_REL, __HIP_MEMORY_SCOPE_AGENT);
        is_last = ((old & (SPLIT - 1)) == (SPLIT - 1)) ? 1 : 0;
    }
    __syncthreads();
    if (!is_last) return;
    __threadfence();                     // acquire: see all other blocks' part writes

    const f32x4* pp = reinterpret_cast<const f32x4*>(part);
    f32x4 acc0 = (f32x4)(0.f), acc1 = (f32x4)(0.f);
    for (int s2 = 0; s2 < SPLIT; ++s2) {
        const size_t base = ((size_t)s2 * B + b) * (H / 4);
        acc0 += pp[base + t];
        acc1 += pp[base + t + 256];
    }
    const float inv = 1.0f / (float)S;
    acc0 *= inv; acc1 *= inv;
    reinterpret_cast<f32x4*>(pooled + (size_t)b * H)[t]       = acc0;
    reinterpret_cast<f32x4*>(pooled + (size_t)b * H)[t + 256] = acc1;
}

// ---------------- Kernel 2: enc1 matvec + last-block-per-b middle chain ----------------
__device__ __forceinline__ float block_sum256(float x, float* red) {
    const int t = threadIdx.x;
    red[t] = x;
    __syncthreads();
    for (int s = 128; s > 0; s >>= 1) {
        if (t < s) red[t] += red[t + s];
        __syncthreads();
    }
    const float r = red[0];
    __syncthreads();
    return r;
}

__global__ __launch_bounds__(256) void enc1_fused(
    const float* __restrict__ pooled,
    const float* __restrict__ ew1, const float* __restrict__ eb1,
    float* __restrict__ out1,
    const float* __restrict__ gu,
    const float* __restrict__ g1,  const float* __restrict__ bb1,
    const float* __restrict__ ew2, const float* __restrict__ eb2,
    const float* __restrict__ emb_tab,
    const float* __restrict__ dw1, const float* __restrict__ db1,
    const float* __restrict__ g2,  const float* __restrict__ bb2,
    float* __restrict__ hs2,
    unsigned int* __restrict__ cnt) {
    __shared__ float red[256];
    __shared__ float hsm[256];
    __shared__ float es[LSYM * EMB];

    const int bid = blockIdx.x;          // 0..511
    const int t   = threadIdx.x;
    const int wv  = t >> 6, lane = t & 63;
    const int bb  = bid >> 6;            // batch of this block (64 blocks per b)

    // ---- main phase: one enc1 output per wave (identical arithmetic to R11)
    {
        const int o  = bid * 4 + wv;     // 0..2047
        const int tt = o & 255;
        const float4* wrow = reinterpret_cast<const float4*>(ew1 + (size_t)tt * H);
        const float4* prow = reinterpret_cast<const float4*>(pooled + bb * H);
        float acc = 0.f;
#pragma unroll
        for (int i = 0; i < 8; ++i) {
            const float4 w = wrow[lane + 64 * i];
            const float4 p = prow[lane + 64 * i];
            acc += w.x * p.x + w.y * p.y + w.z * p.z + w.w * p.w;
        }
        for (int off = 32; off; off >>= 1) acc += __shfl_xor(acc, off, 64);
        if (lane == 0) out1[o] = acc + eb1[tt];
    }

    // ---- tail: last block for this b runs the middle chain
    __syncthreads();
    __threadfence();
    __shared__ int is_last;
    if (t == 0) {
        const unsigned int old = __hip_atomic_fetch_add(&cnt[(8 + bb) * 32], 1u,
                                   __ATOMIC_ACQ_REL, __HIP_MEMORY_SCOPE_AGENT);
        is_last = ((old & 63u) == 63u) ? 1 : 0;
    }
    __syncthreads();
    if (!is_last) return;
    __threadfence();

    const int b = bb;
    float acc = out1[b * 256 + t];
    {   // LN1 + exact GELU
        const float m = block_sum256(acc, red) * (1.0f / 256.0f);
        const float d = acc - m;
        const float v = block_sum256(d * d, red) * (1.0f / 256.0f);
        float x = d * rsqrtf(v + 1e-5f) * g1[t] + bb1[t];
        x = 0.5f * x * (1.0f + erff(x * 0.70710678118654752f));
        hsm[t] = x;
    }
    __syncthreads();

    {   // enc2 + gumbel + per-l argmax + embedding gather
        float a2 = eb2[t];
        const float* w2row = ew2 + t * 256;
        for (int k = 0; k < 256; k += 4) {
            const float4 w = *reinterpret_cast<const float4*>(w2row + k);
            a2 += w.x * hsm[k] + w.y * hsm[k + 1] + w.z * hsm[k + 2] + w.w * hsm[k + 3];
        }
        const float u = gu[b * 256 + t];
        const float z = a2 - logf(-logf(u));
        int   bi = t & 31;
        float bz = z;
        for (int off = 16; off; off >>= 1) {
            const float oz = __shfl_xor(bz, off, 32);
            const int   oi = __shfl_xor(bi, off, 32);
            if (oz > bz || (oz == bz && oi < bi)) { bz = oz; bi = oi; }
        }
        const int l = t >> 5, v32 = t & 31;
        es[l * EMB + v32]      = emb_tab[bi * EMB + v32];
        es[l * EMB + 32 + v32] = emb_tab[bi * EMB + 32 + v32];
    }
    __syncthreads();

    float a3 = db1[t];
    {   // dec1
        const float* d1row = dw1 + t * (LSYM * EMB);
        for (int k = 0; k < LSYM * EMB; k += 4) {
            const float4 w = *reinterpret_cast<const float4*>(d1row + k);
            a3 += w.x * es[k] + w.y * es[k + 1] + w.z * es[k + 2] + w.w * es[k + 3];
        }
    }
    {   // LN2 + exact GELU -> hs2
        const float m2 = block_sum256(a3, red) * (1.0f / 256.0f);
        const float dd = a3 - m2;
        const float vv = block_sum256(dd * dd, red) * (1.0f / 256.0f);
        float y = dd * rsqrtf(vv + 1e-5f) * g2[t] + bb2[t];
        y = 0.5f * y * (1.0f + erff(y * 0.70710678118654752f));
        hs2[b * 256 + t] = y;
    }
}

// ---------------- Kernel 3: dec layer 2 matvec (identical to R11) ----------------
__global__ __launch_bounds__(256) void dec2_matvec(const float* __restrict__ hs2,
                                                   const float* __restrict__ dw2,
                                                   const float* __restrict__ db2,
                                                   float* __restrict__ dec_sc) {
    const int wv   = (blockIdx.x * 256 + threadIdx.x) >> 6;
    const int lane = threadIdx.x & 63;
    const int b = wv >> 11, j = wv & 2047;
    const float4 w = reinterpret_cast<const float4*>(dw2 + (size_t)j * 256)[lane];
    const float4 h = reinterpret_cast<const float4*>(hs2 + b * 256)[lane];
    float acc = w.x * h.x + w.y * h.y + w.z * h.z + w.w * h.w;
    for (int off = 32; off; off >>= 1) acc += __shfl_xor(acc, off, 64);
    if (lane == 0) dec_sc[b * 2048 + j] = 0.1f * (acc + db2[j]);
}

// ---------------- Kernel 4: residual add — plain hid loads (L3 hit), nt out stores ----------------
__global__ __launch_bounds__(256) void residual_add(const float* __restrict__ hid,
                                                    const float* __restrict__ dec,
                                                    float* __restrict__ out) {
    const size_t tid0 = (size_t)blockIdx.x * 256 + threadIdx.x;   // < 2^20
    const int h4 = (int)(tid0 & (H / 4 - 1));
    const f32x4* __restrict__ hv4 = reinterpret_cast<const f32x4*>(hid);
    const float4* __restrict__ dv4 = reinterpret_cast<const float4*>(dec);
    f32x4* __restrict__ ov4 = reinterpret_cast<f32x4*>(out);
    size_t i = tid0;
#pragma unroll
    for (int b = 0; b < B; ++b) {
        const float4 dv = dv4[b * (H / 4) + h4];
        const f32x4 dvv = {dv.x, dv.y, dv.z, dv.w};
#pragma unroll
        for (int r = 0; r < 2; ++r, i += (size_t)1 << 20) {
            const f32x4 hv = hv4[i];            // plain: served from L3 (allocated by pool)
            const f32x4 o = hv + dvv;
            __builtin_nontemporal_store(o, &ov4[i]);   // nt: don't evict hid
        }
    }
}

extern "C" void kernel_launch(void* const* d_in, const int* in_sizes, int n_in,
                              void* d_out, int out_size, void* d_ws, size_t ws_size,
                              hipStream_t stream) {
    const float* hid   = (const float*)d_in[0];
    const float* gu    = (const float*)d_in[1];
    const float* ew1   = (const float*)d_in[2];
    const float* eb1   = (const float*)d_in[3];
    const float* g1    = (const float*)d_in[4];
    const float* bb1   = (const float*)d_in[5];
    const float* ew2   = (const float*)d_in[6];
    const float* eb2   = (const float*)d_in[7];
    const float* emb   = (const float*)d_in[8];
    const float* dw1   = (const float*)d_in[9];
    const float* db1   = (const float*)d_in[10];
    const float* g2    = (const float*)d_in[11];
    const float* bb2   = (const float*)d_in[12];
    const float* dw2   = (const float*)d_in[13];
    const float* db2   = (const float*)d_in[14];
    float* out = (float*)d_out;

    // workspace: [ part: SPLIT*B*H (4 MiB) | pooled: B*H | dec_sc: B*H | out1: 2048 | hs2: 2048 | cnt: 512 u32 ]
    float* part   = (float*)d_ws;
    float* pooled = part + (size_t)SPLIT * B * H;
    float* dec_sc = pooled + (size_t)B * H;
    float* out1   = dec_sc + (size_t)B * H;
    float* hs2    = out1 + (size_t)B * 256;
    unsigned int* cnt = (unsigned int*)(hs2 + (size_t)B * 256);
    // cnt is never reset: each launch adds exactly 64 to each used counter, so the
    // (old & 63) == 63 test fires for exactly one block per launch from ANY start value.

    pool_partial_fused<<<dim3(SPLIT, B), 256, 0, stream>>>(hid, part, pooled, cnt);
    enc1_fused<<<512, 256, 0, stream>>>(pooled, ew1, eb1, out1, gu, g1, bb1, ew2, eb2,
                                        emb, dw1, db1, g2, bb2, hs2, cnt);
    dec2_matvec<<<B * 2048 / 4, 256, 0, stream>>>(hs2, dw2, db2, dec_sc);
    residual_add<<<4096, 256, 0, stream>>>(hid, dec_sc, out);
}

// Round 13
// 179.797 us; speedup vs baseline: 1.5083x; 1.5083x over previous
//
#include <hip/hip_runtime.h>
#include <math.h>

#define B 8
#define S 4096
#define H 2048
#define LSYM 8
#define EMB 64
#define SPLIT 64
#define CHUNK (S / SPLIT)   // 64 rows per slab

typedef float f32x4 __attribute__((ext_vector_type(4)));

// ---------------- Kernel 1: partial pooling over S ----------------
// Plain loads so hid ALLOCATES in L3 (256 MiB, exact fit) for reuse by residual_add
// and by the next graph replay. (R12 counters: ~half of hid survives -> ~130 MB fetch.)
__global__ __launch_bounds__(256) void pool_partial(const float* __restrict__ hid,
                                                    float* __restrict__ part) {
    const int sp = blockIdx.x;          // 0..SPLIT-1
    const int b  = blockIdx.y;
    const int t  = threadIdx.x;
    const float* slab = hid + (size_t)b * S * H + (size_t)sp * CHUNK * H;
    const int iters = CHUNK * (H / 1024);   // 128
    f32x4 a[8];
#pragma unroll
    for (int k = 0; k < 8; ++k) a[k] = (f32x4)(0.f);
    for (int i = 0; i < iters; i += 8) {
#pragma unroll
        for (int k = 0; k < 8; ++k) {
            const f32x4 v = *reinterpret_cast<const f32x4*>(slab + (size_t)(i + k) * 1024 + t * 4);
            a[k] += v;
        }
    }
    const f32x4 e = a[0] + a[2] + a[4] + a[6];
    const f32x4 o = a[1] + a[3] + a[5] + a[7];
    float* dst = part + ((size_t)sp * B + b) * H;
    *reinterpret_cast<f32x4*>(dst + t * 4)        = e;
    *reinterpret_cast<f32x4*>(dst + 1024 + t * 4) = o;
}

// ---------------- Kernel 2: reduce partials -> pooled mean ----------------
__global__ __launch_bounds__(256) void pool_reduce(const float* __restrict__ part,
                                                   float* __restrict__ pooled) {
    const int i4 = blockIdx.x * 256 + threadIdx.x;
    if (i4 >= B * H / 4) return;
    float4 acc = {0.f, 0.f, 0.f, 0.f};
    for (int sp = 0; sp < SPLIT; ++sp) {
        const float4 v = *reinterpret_cast<const float4*>(part + (size_t)sp * B * H + (size_t)i4 * 4);
        acc.x += v.x; acc.y += v.y; acc.z += v.z; acc.w += v.w;
    }
    const float inv = 1.0f / (float)S;
    acc.x *= inv; acc.y *= inv; acc.z *= inv; acc.w *= inv;
    *reinterpret_cast<float4*>(pooled + (size_t)i4 * 4) = acc;
}

// ---------------- Kernel 3a: enc layer 1 matvec, one wave per output ----------------
__global__ __launch_bounds__(256) void enc1_matvec(const float* __restrict__ pooled,
                                                   const float* __restrict__ ew1,
                                                   const float* __restrict__ eb1,
                                                   float* __restrict__ out1) {
    const int wv   = (blockIdx.x * 256 + threadIdx.x) >> 6;
    const int lane = threadIdx.x & 63;
    const int b = wv >> 8, t = wv & 255;
    const float4* wrow = reinterpret_cast<const float4*>(ew1 + (size_t)t * H);
    const float4* prow = reinterpret_cast<const float4*>(pooled + b * H);
    float acc = 0.f;
#pragma unroll
    for (int i = 0; i < 8; ++i) {
        const float4 w = wrow[lane + 64 * i];
        const float4 p = prow[lane + 64 * i];
        acc += w.x * p.x + w.y * p.y + w.z * p.z + w.w * p.w;
    }
    for (int off = 32; off; off >>= 1) acc += __shfl_xor(acc, off, 64);
    if (lane == 0) out1[b * 256 + t] = acc + eb1[t];
}

// ---------------- Kernel 3b: middle chain ----------------
__device__ __forceinline__ float block_sum256(float x, float* red) {
    const int t = threadIdx.x;
    red[t] = x;
    __syncthreads();
    for (int s = 128; s > 0; s >>= 1) {
        if (t < s) red[t] += red[t + s];
        __syncthreads();
    }
    const float r = red[0];
    __syncthreads();
    return r;
}

__global__ __launch_bounds__(256) void mlp_middle(
    const float* __restrict__ out1, const float* __restrict__ gu,
    const float* __restrict__ g1,  const float* __restrict__ bb1,
    const float* __restrict__ ew2, const float* __restrict__ eb2,
    const float* __restrict__ emb_tab,
    const float* __restrict__ dw1, const float* __restrict__ db1,
    const float* __restrict__ g2,  const float* __restrict__ bb2,
    float* __restrict__ hs2) {
    __shared__ float red[256];
    __shared__ float hs[256];
    __shared__ float es[LSYM * EMB];

    const int b = blockIdx.x;
    const int t = threadIdx.x;

    float acc = out1[b * 256 + t];
    {
        const float m = block_sum256(acc, red) * (1.0f / 256.0f);
        const float d = acc - m;
        const float v = block_sum256(d * d, red) * (1.0f / 256.0f);
        float x = d * rsqrtf(v + 1e-5f) * g1[t] + bb1[t];
        x = 0.5f * x * (1.0f + erff(x * 0.70710678118654752f));
        hs[t] = x;
    }
    __syncthreads();

    float z;
    {
        float a2 = eb2[t];
        const float* w2row = ew2 + t * 256;
        for (int k = 0; k < 256; k += 4) {
            const float4 w = *reinterpret_cast<const float4*>(w2row + k);
            a2 += w.x * hs[k] + w.y * hs[k + 1] + w.z * hs[k + 2] + w.w * hs[k + 3];
        }
        const float u = gu[b * 256 + t];
        z = a2 - logf(-logf(u));
    }

    {
        int   bi = t & 31;
        float bz = z;
        for (int off = 16; off; off >>= 1) {
            const float oz = __shfl_xor(bz, off, 32);
            const int   oi = __shfl_xor(bi, off, 32);
            if (oz > bz || (oz == bz && oi < bi)) { bz = oz; bi = oi; }
        }
        const int l = t >> 5, v32 = t & 31;
        es[l * EMB + v32]      = emb_tab[bi * EMB + v32];
        es[l * EMB + 32 + v32] = emb_tab[bi * EMB + 32 + v32];
    }
    __syncthreads();

    float a3 = db1[t];
    {
        const float* d1row = dw1 + t * (LSYM * EMB);
        for (int k = 0; k < LSYM * EMB; k += 4) {
            const float4 w = *reinterpret_cast<const float4*>(d1row + k);
            a3 += w.x * es[k] + w.y * es[k + 1] + w.z * es[k + 2] + w.w * es[k + 3];
        }
    }
    {
        const float m2 = block_sum256(a3, red) * (1.0f / 256.0f);
        const float dd = a3 - m2;
        const float vv = block_sum256(dd * dd, red) * (1.0f / 256.0f);
        float y = dd * rsqrtf(vv + 1e-5f) * g2[t] + bb2[t];
        y = 0.5f * y * (1.0f + erff(y * 0.70710678118654752f));
        hs2[b * 256 + t] = y;
    }
}

// ---------------- Kernel 3c: dec layer 2 matvec, one wave per output ----------------
__global__ __launch_bounds__(256) void dec2_matvec(const float* __restrict__ hs2,
                                                   const float* __restrict__ dw2,
                                                   const float* __restrict__ db2,
                                                   float* __restrict__ dec_sc) {
    const int wv   = (blockIdx.x * 256 + threadIdx.x) >> 6;
    const int lane = threadIdx.x & 63;
    const int b = wv >> 11, j = wv & 2047;
    const float4 w = reinterpret_cast<const float4*>(dw2 + (size_t)j * 256)[lane];
    const float4 h = reinterpret_cast<const float4*>(hs2 + b * 256)[lane];
    float acc = w.x * h.x + w.y * h.y + w.z * h.z + w.w * h.w;
    for (int off = 32; off; off >>= 1) acc += __shfl_xor(acc, off, 64);
    if (lane == 0) dec_sc[b * 2048 + j] = 0.1f * (acc + db2[j]);
}

// ---------------- Kernel 4: residual add — plain hid loads (L3 reuse), nt out stores ----------------
__global__ __launch_bounds__(256) void residual_add(const float* __restrict__ hid,
                                                    const float* __restrict__ dec,
                                                    float* __restrict__ out) {
    const size_t tid0 = (size_t)blockIdx.x * 256 + threadIdx.x;   // < 2^20
    const int h4 = (int)(tid0 & (H / 4 - 1));
    const f32x4* __restrict__ hv4 = reinterpret_cast<const f32x4*>(hid);
    const float4* __restrict__ dv4 = reinterpret_cast<const float4*>(dec);
    f32x4* __restrict__ ov4 = reinterpret_cast<f32x4*>(out);
    size_t i = tid0;
#pragma unroll
    for (int b = 0; b < B; ++b) {
        const float4 dv = dv4[b * (H / 4) + h4];
        const f32x4 dvv = {dv.x, dv.y, dv.z, dv.w};
#pragma unroll
        for (int r = 0; r < 2; ++r, i += (size_t)1 << 20) {
            const f32x4 hv = hv4[i];            // plain: may hit L3 (allocated by pool_partial)
            const f32x4 o = hv + dvv;
            __builtin_nontemporal_store(o, &ov4[i]);   // nt: out stream must not evict hid
        }
    }
}

extern "C" void kernel_launch(void* const* d_in, const int* in_sizes, int n_in,
                              void* d_out, int out_size, void* d_ws, size_t ws_size,
                              hipStream_t stream) {
    const float* hid   = (const float*)d_in[0];
    const float* gu    = (const float*)d_in[1];
    const float* ew1   = (const float*)d_in[2];
    const float* eb1   = (const float*)d_in[3];
    const float* g1    = (const float*)d_in[4];
    const float* bb1   = (const float*)d_in[5];
    const float* ew2   = (const float*)d_in[6];
    const float* eb2   = (const float*)d_in[7];
    const float* emb   = (const float*)d_in[8];
    const float* dw1   = (const float*)d_in[9];
    const float* db1   = (const float*)d_in[10];
    const float* g2    = (const float*)d_in[11];
    const float* bb2   = (const float*)d_in[12];
    const float* dw2   = (const float*)d_in[13];
    const float* db2   = (const float*)d_in[14];
    float* out = (float*)d_out;

    // workspace: [ part: SPLIT*B*H (4 MiB) | pooled: B*H | dec_sc: B*H | out1: B*256 | hs2: B*256 ]
    float* part   = (float*)d_ws;
    float* pooled = part + (size_t)SPLIT * B * H;
    float* dec_sc = pooled + (size_t)B * H;
    float* out1   = dec_sc + (size_t)B * H;
    float* hs2    = out1 + (size_t)B * 256;

    pool_partial<<<dim3(SPLIT, B), 256, 0, stream>>>(hid, part);
    pool_reduce<<<(B * H / 4 + 255) / 256, 256, 0, stream>>>(part, pooled);
    enc1_matvec<<<B * 256 / 4, 256, 0, stream>>>(pooled, ew1, eb1, out1);
    mlp_middle<<<B, 256, 0, stream>>>(out1, gu, g1, bb1, ew2, eb2, emb,
                                      dw1, db1, g2, bb2, hs2);
    dec2_matvec<<<B * 2048 / 4, 256, 0, stream>>>(hs2, dw2, db2, dec_sc);
    residual_add<<<4096, 256, 0, stream>>>(hid, dec_sc, out);
}